// Round 6
// baseline (147.713 us; speedup 1.0000x reference)
//
#include <hip/hip_runtime.h>
#include <hip/hip_bf16.h>

#define NPTS 131072
#define K 27
#define CIN 64
#define COUT 128
#define BM 64                 // rows per conv block

constexpr float BN_EPS = 1e-5f;
constexpr float NEG_SLOPE = 0.01f;

typedef __attribute__((ext_vector_type(8))) short short8;
typedef __attribute__((ext_vector_type(4))) float f32x4;

__device__ inline unsigned int pk_bf16(float a, float b) {
    __hip_bfloat16 ha = __float2bfloat16(a), hb = __float2bfloat16(b);
    unsigned short ua = *reinterpret_cast<unsigned short*>(&ha);
    unsigned short ub = *reinterpret_cast<unsigned short*>(&hb);
    return (unsigned int)ua | ((unsigned int)ub << 16);
}

// ---------------------------------------------------------------------------
// prep_w: W [27][64][128] f32 -> Wt [27][128][64] bf16
// ---------------------------------------------------------------------------
__global__ __launch_bounds__(256) void prep_w(
    const float* __restrict__ W, unsigned short* __restrict__ Wt)
{
    int o = blockIdx.x * 256 + threadIdx.x;           // 27*128*64 = 221184
    if (o >= K * COUT * CIN) return;
    int k  = o / (COUT * CIN);
    int r  = o % (COUT * CIN);
    int co = r / CIN;
    int ci = r % CIN;
    __hip_bfloat16 h = __float2bfloat16(W[(k * CIN + ci) * COUT + co]);
    Wt[o] = *reinterpret_cast<unsigned short*>(&h);
}

// ---------------------------------------------------------------------------
// prep_f: feats f32 -> bf16 (row NPTS is the zero sentinel, memset'd)
// ---------------------------------------------------------------------------
__global__ __launch_bounds__(256) void prep_f(
    const float* __restrict__ feats, unsigned short* __restrict__ featsb)
{
    size_t t = (size_t)blockIdx.x * 256 + threadIdx.x;   // 1,048,576 threads
    const float4* src = (const float4*)(feats) + t * 2;
    float4 v0 = src[0], v1 = src[1];
    uint4 o;
    o.x = pk_bf16(v0.x, v0.y); o.y = pk_bf16(v0.z, v0.w);
    o.z = pk_bf16(v1.x, v1.y); o.w = pk_bf16(v1.z, v1.w);
    ((uint4*)featsb)[t] = o;
}

// ---------------------------------------------------------------------------
// prep_idx: fold mask into index (masked-off -> sentinel zero row NPTS)
// ---------------------------------------------------------------------------
__global__ __launch_bounds__(256) void prep_idx(
    const int* __restrict__ nidx, const int* __restrict__ nmask,
    int* __restrict__ midx)
{
    int t = blockIdx.x * 256 + threadIdx.x;              // 3,538,944
    if (t < NPTS * K) midx[t] = nmask[t] ? nidx[t] : NPTS;
}

// ---------------------------------------------------------------------------
// conv: MFMA gather-conv, 256 thr = 4 waves (2x2), 64x128 tile, fused stats.
// 2-DEEP A prefetch (named reg sets aA/aB, k-loop unrolled by pairs): the
// ~900-cycle HBM gather for k+2 is issued at iteration k, giving two full
// iterations (~900 cy) of cover.  B (L2-hot Wt) stays 1-deep.
// ---------------------------------------------------------------------------
template<bool MIDX>
__global__ __launch_bounds__(256) void conv_kernel(
    const unsigned short* __restrict__ featsb,   // NPTS+1 rows (last = zeros)
    const int* __restrict__ midx,                // if MIDX
    const int* __restrict__ nidx,                // else
    const int* __restrict__ nmask,
    const unsigned short* __restrict__ Wt,
    float* __restrict__ y,
    float* __restrict__ accum)                   // [256]: sums then sumsqs
{
    __shared__ unsigned char Alds[BM * CIN * 2];      // 8 KB
    __shared__ unsigned char Blds[COUT * CIN * 2];    // 16 KB (total 24 KB)

    const int tid  = threadIdx.x;
    const int l    = tid & 63;
    const int wid  = tid >> 6;
    const int wr   = wid >> 1;
    const int wc   = wid & 1;
    const int base = blockIdx.x * BM;

    const int arow = tid >> 2;        // 4 threads/row, 32 B each
    const int aq   = tid & 3;
    const int bcol = tid >> 1;        // 2 threads/col, 64 B each
    const int bh   = tid & 1;

    auto loadIdx = [&](int kq) -> int {
        kq = kq < K ? kq : K - 1;     // clamped: harmless redundant load
        int o = (base + arow) * K + kq;
        if constexpr (MIDX) return midx[o];
        else                return nmask[o] ? nidx[o] : NPTS;
    };

    const int aswz = (arow & 7) << 4;
    unsigned char* ap = Alds + arow * 128;
    const int bswz = (bcol & 7) << 4;
    unsigned char* bp = Blds + bcol * 128;

    // ---- pipeline helpers -------------------------------------------------
    uint4 aA0, aA1;                   // A data for even k
    uint4 aB0, aB1;                   // A data for odd k
    uint4 b0, b1, b2, b3;             // B data for next iteration
    int   idE, idO;                   // gather ids: next even / next odd slot

#define ISSUE_A(id, x0, x1)                                                   \
    { const uint4* p_ = (const uint4*)(featsb + (size_t)(id) * CIN) + aq * 2; \
      x0 = p_[0]; x1 = p_[1]; }
#define ISSUE_B(kq)                                                           \
    { int kk_ = (kq) < K ? (kq) : K - 1;                                      \
      const uint4* p_ = (const uint4*)(Wt + ((size_t)kk_ * COUT + bcol) * CIN) + bh * 4; \
      b0 = p_[0]; b1 = p_[1]; b2 = p_[2]; b3 = p_[3]; }

    f32x4 acc[2][4];
#pragma unroll
    for (int m = 0; m < 2; ++m)
#pragma unroll
        for (int n = 0; n < 4; ++n) acc[m][n] = (f32x4)0.f;

#define MFMA_TILE()                                                           \
    _Pragma("unroll")                                                         \
    for (int ks = 0; ks < 2; ++ks) {                                          \
        const int kbyte = ks * 64 + (l >> 4) * 16;                            \
        short8 a[2], b[4];                                                    \
        _Pragma("unroll")                                                     \
        for (int m = 0; m < 2; ++m) {                                         \
            int row = wr * 32 + m * 16 + (l & 15);                            \
            a[m] = *(const short8*)(Alds + row * 128 + (kbyte ^ ((row & 7) << 4))); \
        }                                                                     \
        _Pragma("unroll")                                                     \
        for (int n = 0; n < 4; ++n) {                                         \
            int col = wc * 64 + n * 16 + (l & 15);                            \
            b[n] = *(const short8*)(Blds + col * 128 + (kbyte ^ ((col & 7) << 4))); \
        }                                                                     \
        _Pragma("unroll")                                                     \
        for (int m = 0; m < 2; ++m)                                           \
            _Pragma("unroll")                                                 \
            for (int n = 0; n < 4; ++n)                                       \
                acc[m][n] = __builtin_amdgcn_mfma_f32_16x16x32_bf16(          \
                    a[m], b[n], acc[m][n], 0, 0, 0);                          \
    }

#define WRITE_A(x0, x1)                                                       \
    { *(uint4*)(ap + ((aq * 32 +  0) ^ aswz)) = x0;                           \
      *(uint4*)(ap + ((aq * 32 + 16) ^ aswz)) = x1; }
#define WRITE_B()                                                             \
    { *(uint4*)(bp + ((bh * 64 +  0) ^ bswz)) = b0;                           \
      *(uint4*)(bp + ((bh * 64 + 16) ^ bswz)) = b1;                           \
      *(uint4*)(bp + ((bh * 64 + 32) ^ bswz)) = b2;                           \
      *(uint4*)(bp + ((bh * 64 + 48) ^ bswz)) = b3; }

    // ---- prologue: A(0), A(1), B(0) in flight; ids for k=2,3 ----
    {
        int id0 = loadIdx(0);
        int id1 = loadIdx(1);
        ISSUE_A(id0, aA0, aA1);
        ISSUE_A(id1, aB0, aB1);
        ISSUE_B(0);
        idE = loadIdx(2);
        idO = loadIdx(3);
    }

    // ---- main loop: pairs k, k+1 for k = 0..24 ----
    for (int k = 0; k < K - 1; k += 2) {
        // even iteration k
        __syncthreads();
        WRITE_A(aA0, aA1);
        WRITE_B();
        ISSUE_A(idE, aA0, aA1);       // A(k+2), lands by iter k+2
        ISSUE_B(k + 1);
        idE = loadIdx(k + 4);
        __syncthreads();
        MFMA_TILE();

        // odd iteration k+1
        __syncthreads();
        WRITE_A(aB0, aB1);
        WRITE_B();
        ISSUE_A(idO, aB0, aB1);       // A(k+3)
        ISSUE_B(k + 2);
        idO = loadIdx(k + 5);
        __syncthreads();
        MFMA_TILE();
    }
    // ---- tail: k = 26 ----
    {
        __syncthreads();
        WRITE_A(aA0, aA1);
        WRITE_B();
        __syncthreads();
        MFMA_TILE();
    }

    // ---- y write: C/D layout col=l&15, row=(l>>4)*4+r ----
#pragma unroll
    for (int m = 0; m < 2; ++m)
#pragma unroll
        for (int n = 0; n < 4; ++n) {
            int gcol = wc * 64 + n * 16 + (l & 15);
#pragma unroll
            for (int r = 0; r < 4; ++r) {
                int grow = base + wr * 32 + m * 16 + (l >> 4) * 4 + r;
                y[(size_t)grow * COUT + gcol] = acc[m][n][r];
            }
        }

    // ---- fused per-block BN stats (reuse Alds as the combine buffer) ----
    float sv[4], s2v[4];
#pragma unroll
    for (int n = 0; n < 4; ++n) {
        float s = 0.f, s2 = 0.f;
#pragma unroll
        for (int m = 0; m < 2; ++m)
#pragma unroll
            for (int r = 0; r < 4; ++r) { float v = acc[m][n][r]; s += v; s2 += v * v; }
        s  += __shfl_xor(s, 16);  s  += __shfl_xor(s, 32);
        s2 += __shfl_xor(s2, 16); s2 += __shfl_xor(s2, 32);
        sv[n] = s; s2v[n] = s2;
    }
    __syncthreads();                  // everyone done reading Alds/Blds
    float* statf = (float*)Alds;      // [2][2][128] = 4 KB
    if (l < 16) {
#pragma unroll
        for (int n = 0; n < 4; ++n) {
            int c = wc * 64 + n * 16 + l;
            statf[(0 * 2 + wr) * 128 + c] = sv[n];
            statf[(1 * 2 + wr) * 128 + c] = s2v[n];
        }
    }
    __syncthreads();
    if (tid < 128) {
        atomicAdd(&accum[tid],       statf[0 * 128 + tid] + statf[1 * 128 + tid]);
        atomicAdd(&accum[128 + tid], statf[2 * 128 + tid] + statf[3 * 128 + tid]);
    }
#undef ISSUE_A
#undef ISSUE_B
#undef WRITE_A
#undef WRITE_B
#undef MFMA_TILE
}

// ---------------------------------------------------------------------------
// finalize: fold mean/var/gamma/beta into per-channel scale+bias
// ---------------------------------------------------------------------------
__global__ void finalize_kernel(const float* __restrict__ accum,
                                const float* __restrict__ gamma,
                                const float* __restrict__ beta,
                                float* __restrict__ sb)
{
    int c = threadIdx.x;                      // 128 threads
    float invN  = 1.0f / (float)NPTS;
    float mean  = accum[c] * invN;
    float var   = accum[128 + c] * invN - mean * mean;
    float scale = gamma[c] * rsqrtf(var + BN_EPS);
    sb[c]       = scale;
    sb[128 + c] = beta[c] - mean * scale;
}

// ---------------------------------------------------------------------------
// bn: y = leaky(y*scale+bias), float4-vectorized, scale/bias in registers
// ---------------------------------------------------------------------------
__global__ __launch_bounds__(256) void bn_kernel(
    float* __restrict__ y, const float* __restrict__ sb)
{
    size_t start = (size_t)blockIdx.x * blockDim.x + threadIdx.x;
    int c0 = (int)((start * 4) & (COUT - 1));   // invariant under grid stride
    float sc[4], bi[4];
#pragma unroll
    for (int j = 0; j < 4; ++j) { sc[j] = sb[c0 + j]; bi[j] = sb[COUT + c0 + j]; }

    const size_t total = (size_t)NPTS * COUT / 4;
    const size_t step  = (size_t)gridDim.x * blockDim.x;
    for (size_t idx = start; idx < total; idx += step) {
        float4 v = ((const float4*)y)[idx];
        v.x = v.x * sc[0] + bi[0]; v.x = v.x > 0.f ? v.x : NEG_SLOPE * v.x;
        v.y = v.y * sc[1] + bi[1]; v.y = v.y > 0.f ? v.y : NEG_SLOPE * v.y;
        v.z = v.z * sc[2] + bi[2]; v.z = v.z > 0.f ? v.z : NEG_SLOPE * v.z;
        v.w = v.w * sc[3] + bi[3]; v.w = v.w > 0.f ? v.w : NEG_SLOPE * v.w;
        ((float4*)y)[idx] = v;
    }
}

extern "C" void kernel_launch(void* const* d_in, const int* in_sizes, int n_in,
                              void* d_out, int out_size, void* d_ws, size_t ws_size,
                              hipStream_t stream)
{
    const float* feats = (const float*)d_in[0];
    const int*   nidx  = (const int*)d_in[1];
    const int*   nmask = (const int*)d_in[2];
    const float* W     = (const float*)d_in[3];
    const float* gamma = (const float*)d_in[4];
    const float* beta  = (const float*)d_in[5];

    float* y = (float*)d_out;

    // ws layout
    float*          accum  = (float*)d_ws;                               // 1 KB
    float*          sb     = (float*)((char*)d_ws + 1024);               // 1 KB
    unsigned short* Wt     = (unsigned short*)((char*)d_ws + 4096);      // 442 KB
    unsigned short* featsb = (unsigned short*)((char*)d_ws + 458752);    // 16.78 MB (NPTS+1 rows)
    int*            midx   = (int*)((char*)d_ws + 17236224);             // 14.16 MB
    const size_t need_midx = 17236224 + (size_t)NPTS * K * sizeof(int);
    const bool use_midx = ws_size >= need_midx;

    hipMemsetAsync(accum, 0, 2 * COUT * sizeof(float), stream);
    hipMemsetAsync(featsb + (size_t)NPTS * CIN, 0, CIN * 2, stream);   // zero sentinel row

    prep_w<<<(K * COUT * CIN + 255) / 256, 256, 0, stream>>>(W, Wt);
    prep_f<<<(NPTS * CIN / 8) / 256, 256, 0, stream>>>(feats, featsb);
    if (use_midx) {
        prep_idx<<<(NPTS * K + 255) / 256, 256, 0, stream>>>(nidx, nmask, midx);
        conv_kernel<true><<<NPTS / BM, 256, 0, stream>>>(featsb, midx, nidx, nmask, Wt, y, accum);
    } else {
        conv_kernel<false><<<NPTS / BM, 256, 0, stream>>>(featsb, midx, nidx, nmask, Wt, y, accum);
    }
    finalize_kernel<<<1, 128, 0, stream>>>(accum, gamma, beta, sb);
    bn_kernel<<<2048, 256, 0, stream>>>(y, sb);
}